// Round 1
// baseline (320.130 us; speedup 1.0000x reference)
//
#include <hip/hip_runtime.h>

#define NV 20000
#define NC 300
#define NI 10000
#define NN 30300   // NV + NC + NI
#define NE 1000000
#define D  64

// ---------------- zero first half of output (all_embs[:NV] == 0 structurally) ----
__global__ void zero_kernel(float4* __restrict__ out, int n4) {
    int i = blockIdx.x * blockDim.x + threadIdx.x;
    if (i < n4) out[i] = make_float4(0.f, 0.f, 0.f, 0.f);
}

// ---------------- build initial all_off = relu(concat(offsets)) ------------------
__global__ void init_off_kernel(const float4* __restrict__ vo, const float4* __restrict__ co,
                                const float4* __restrict__ io, float4* __restrict__ buf) {
    int i = blockIdx.x * blockDim.x + threadIdx.x;   // over NN*16 float4s
    if (i >= NN * 16) return;
    int n = i >> 4;
    float4 v;
    if (n < NV)            v = vo[i];
    else if (n < NV + NC)  v = co[i - NV * 16];
    else                   v = io[i - (NV + NC) * 16];
    v.x = fmaxf(v.x, 0.f); v.y = fmaxf(v.y, 0.f);
    v.z = fmaxf(v.z, 0.f); v.w = fmaxf(v.w, 0.f);
    buf[i] = v;
}

// ---------------- CSR build: count, scan, scatter --------------------------------
__global__ void count_kernel(const int* __restrict__ head, int* __restrict__ counts) {
    int e = blockIdx.x * blockDim.x + threadIdx.x;
    if (e < NE) atomicAdd(&counts[head[e]], 1);
}

__global__ void scan_kernel(const int* __restrict__ counts, int* __restrict__ offsets) {
    __shared__ int lds[1024];
    __shared__ int carry_s;
    if (threadIdx.x == 0) carry_s = 0;
    __syncthreads();
    for (int base = 0; base < NN; base += 1024) {
        int i = base + threadIdx.x;
        int v = (i < NN) ? counts[i] : 0;
        lds[threadIdx.x] = v;
        __syncthreads();
        for (int off = 1; off < 1024; off <<= 1) {
            int t = (threadIdx.x >= off) ? lds[threadIdx.x - off] : 0;
            __syncthreads();
            lds[threadIdx.x] += t;
            __syncthreads();
        }
        int carry = carry_s;
        int excl = lds[threadIdx.x] - v;
        if (i < NN) offsets[i] = carry + excl;
        __syncthreads();
        if (threadIdx.x == 0) carry_s = carry + lds[1023];
        __syncthreads();
    }
    if (threadIdx.x == 0) offsets[NN] = carry_s;
}

__global__ void cursor_kernel(const int* __restrict__ offsets, int* __restrict__ cursor) {
    int i = blockIdx.x * blockDim.x + threadIdx.x;
    if (i < NN) cursor[i] = offsets[i];
}

__global__ void scatter_kernel(const int* __restrict__ head, const int* __restrict__ tail,
                               int* __restrict__ cursor, int* __restrict__ stails) {
    int e = blockIdx.x * blockDim.x + threadIdx.x;
    if (e < NE) {
        int h = head[e];
        int p = atomicAdd(&cursor[h], 1);
        stails[p] = tail[e];
    }
}

// ---------------- one hop: per-node segmented max (or min for icd nodes) ---------
// One wave (64 lanes) per node; lane = feature dim. Coalesced 256B row gathers.
__global__ void hop_kernel(const float* __restrict__ prev, const int* __restrict__ offsets,
                           const int* __restrict__ stails, float* __restrict__ out, int nNodes) {
    int wid  = blockIdx.x * (blockDim.x >> 6) + (threadIdx.x >> 6);
    int lane = threadIdx.x & 63;
    if (wid >= nNodes) return;
    int start = offsets[wid], end = offsets[wid + 1];
    bool isMin = (wid >= NV + NC);
    float acc = isMin ? __builtin_inff() : 0.0f;
    for (int k = start; k < end; k += 64) {
        int m = end - k; if (m > 64) m = 64;
        int tv = (lane < m) ? stails[k + lane] : 0;
        int j = 0;
        for (; j + 4 <= m; j += 4) {
            int t0 = __shfl(tv, j), t1 = __shfl(tv, j + 1);
            int t2 = __shfl(tv, j + 2), t3 = __shfl(tv, j + 3);
            float v0 = prev[t0 * D + lane];
            float v1 = prev[t1 * D + lane];
            float v2 = prev[t2 * D + lane];
            float v3 = prev[t3 * D + lane];
            if (isMin) acc = fminf(acc, fminf(fminf(v0, v1), fminf(v2, v3)));
            else       acc = fmaxf(acc, fmaxf(fmaxf(v0, v1), fmaxf(v2, v3)));
        }
        for (; j < m; ++j) {
            int t = __shfl(tv, j);
            float v = prev[t * D + lane];
            acc = isMin ? fminf(acc, v) : fmaxf(acc, v);
        }
    }
    if (isMin && start == end) acc = 0.0f;   // empty segment -> 0 (isfinite fixup)
    out[wid * D + lane] = acc;
}

extern "C" void kernel_launch(void* const* d_in, const int* in_sizes, int n_in,
                              void* d_out, int out_size, void* d_ws, size_t ws_size,
                              hipStream_t stream) {
    const float* visit_offset = (const float*)d_in[1];
    const float* ccs_offset   = (const float*)d_in[3];
    const float* icd_offset   = (const float*)d_in[5];
    const int*   head         = (const int*)d_in[6];
    const int*   tail         = (const int*)d_in[7];
    float*       out          = (float*)d_out;

    char* ws = (char*)d_ws;
    size_t offTab = (size_t)NN * D * sizeof(float);       // 7,756,800 B (256-aligned)
    float* off0    = (float*)(ws);
    float* off1    = (float*)(ws + offTab);
    int*   stails  = (int*)  (ws + 2 * offTab);
    int*   counts  = (int*)  (ws + 2 * offTab + (size_t)NE * sizeof(int));
    int*   offsets = counts + NN + 64;                    // padded apart
    int*   cursor  = offsets + NN + 1 + 63;

    hipMemsetAsync(counts, 0, NN * sizeof(int), stream);

    zero_kernel<<<(NV * 16 + 255) / 256, 256, 0, stream>>>((float4*)out, NV * 16);
    init_off_kernel<<<(NN * 16 + 255) / 256, 256, 0, stream>>>(
        (const float4*)visit_offset, (const float4*)ccs_offset, (const float4*)icd_offset,
        (float4*)off0);
    count_kernel<<<(NE + 255) / 256, 256, 0, stream>>>(head, counts);
    scan_kernel<<<1, 1024, 0, stream>>>(counts, offsets);
    cursor_kernel<<<(NN + 255) / 256, 256, 0, stream>>>(offsets, cursor);
    scatter_kernel<<<(NE + 255) / 256, 256, 0, stream>>>(head, tail, cursor, stails);

    // hop 1: all NN nodes, off0 -> off1
    hop_kernel<<<(NN + 3) / 4, 256, 0, stream>>>(off0, offsets, stails, off1, NN);
    // hop 2: only visit nodes matter for the output; write directly into d_out
    hop_kernel<<<(NV + 3) / 4, 256, 0, stream>>>(off1, offsets, stails, out + (size_t)NV * D, NV);
}

// Round 4
// 176.161 us; speedup vs baseline: 1.8173x; 1.8173x over previous
//
#include <hip/hip_runtime.h>

#define NV 20000
#define NC 300
#define NI 10000
#define NN 30300   // NV + NC + NI
#define NE 1000000
#define D  64

#define NB     128          // buckets for CSR build
#define BNODES 237          // ceil(NN / NB); 128*237 = 30336 >= 30300
#define CAP    12288        // per-bucket edge capacity (mean 7822, +50 sigma)
#define BIN_CHUNK 2048
#define NBLK_BIN ((NE + BIN_CHUNK - 1) / BIN_CHUNK)   // 489

__device__ __forceinline__ unsigned short f2bf(float x) {
    // round-to-nearest-even f32 -> bf16; x is finite and >= 0 here
    unsigned u = __float_as_uint(x);
    u += 0x7FFFu + ((u >> 16) & 1u);
    return (unsigned short)(u >> 16);
}

// ---------------- output[:NV*D] = 0 (all_embs half is structurally zero) ---------
__global__ void zero_kernel(float4* __restrict__ out, int n4) {
    int i = blockIdx.x * blockDim.x + threadIdx.x;
    if (i < n4) out[i] = make_float4(0.f, 0.f, 0.f, 0.f);
}

// ---------------- all_off = relu(concat(offsets)) as bf16 bits -------------------
__global__ void init_off_kernel(const float4* __restrict__ vo, const float4* __restrict__ co,
                                const float4* __restrict__ io, unsigned short* __restrict__ buf) {
    int i = blockIdx.x * blockDim.x + threadIdx.x;   // over NN*16 float4s
    if (i >= NN * 16) return;
    int n = i >> 4;
    float4 v;
    if (n < NV)            v = vo[i];
    else if (n < NV + NC)  v = co[i - NV * 16];
    else                   v = io[i - (NV + NC) * 16];
    ushort4 o;
    o.x = f2bf(fmaxf(v.x, 0.f));
    o.y = f2bf(fmaxf(v.y, 0.f));
    o.z = f2bf(fmaxf(v.z, 0.f));
    o.w = f2bf(fmaxf(v.w, 0.f));
    *reinterpret_cast<ushort4*>(buf + (size_t)i * 4) = o;
}

// ---------------- pass B: bin edges into 128 bucket regions (packed head|tail) ---
__global__ void bin_kernel(const int* __restrict__ head, const int* __restrict__ tail,
                           int* __restrict__ gcur, unsigned* __restrict__ pairs) {
    __shared__ int hist[NB];
    __shared__ int base[NB];
    int t = threadIdx.x;
    int e0 = blockIdx.x * BIN_CHUNK;
    if (t < NB) hist[t] = 0;
    __syncthreads();
    int hs[8], ts[8];
#pragma unroll
    for (int i = 0; i < 8; i++) {
        int e = e0 + i * 256 + t;
        if (e < NE) {
            hs[i] = head[e]; ts[i] = tail[e];
            atomicAdd(&hist[hs[i] / BNODES], 1);
        } else hs[i] = -1;
    }
    __syncthreads();
    if (t < NB) {
        int c = hist[t];
        base[t] = c ? atomicAdd(&gcur[t], c) : 0;
        hist[t] = 0;   // reuse as local cursor
    }
    __syncthreads();
#pragma unroll
    for (int i = 0; i < 8; i++) {
        if (hs[i] >= 0) {
            int b = hs[i] / BNODES;
            int pos = base[b] + atomicAdd(&hist[b], 1);
            if (pos < CAP)
                pairs[(size_t)b * CAP + pos] = ((unsigned)hs[i] << 15) | (unsigned)ts[i];
        }
    }
}

// ---------------- pass C: per-bucket node sort in LDS -> CSR (no amplification) --
__global__ void bucket_sort_kernel(const unsigned* __restrict__ pairs, const int* __restrict__ gcur,
                                   unsigned short* __restrict__ stails,
                                   int* __restrict__ starts, int* __restrict__ ends) {
    __shared__ unsigned short staging[CAP];   // 24 KB
    __shared__ int cnt_l[256];
    __shared__ int scan_s[256];
    __shared__ int cur[256];
    int b = blockIdx.x, t = threadIdx.x;
    int node0 = b * BNODES;
    int nn = min(BNODES, NN - node0);
    int cnt = min(gcur[b], CAP);
    cnt_l[t] = 0;
    __syncthreads();
    const unsigned* P = pairs + (size_t)b * CAP;
    for (int i = t; i < cnt; i += 256) {
        int local = (int)(P[i] >> 15) - node0;
        atomicAdd(&cnt_l[local], 1);
    }
    __syncthreads();
    int v = cnt_l[t];
    scan_s[t] = v;
    __syncthreads();
    for (int off = 1; off < 256; off <<= 1) {
        int tv = (t >= off) ? scan_s[t - off] : 0;
        __syncthreads();
        scan_s[t] += tv;
        __syncthreads();
    }
    int excl = scan_s[t] - v;
    cur[t] = excl;
    if (t < nn) {
        starts[node0 + t] = b * CAP + excl;
        ends[node0 + t]   = b * CAP + excl + v;
    }
    __syncthreads();
    for (int i = t; i < cnt; i += 256) {
        unsigned p = P[i];
        int local = (int)(p >> 15) - node0;
        int pos = atomicAdd(&cur[local], 1);
        staging[pos] = (unsigned short)(p & 0x7FFFu);
    }
    __syncthreads();
    for (int i = t; i < cnt; i += 256)
        stails[(size_t)b * CAP + i] = staging[i];
}

// ---------------- one hop: per-node segmented max/min on bf16 bit patterns -------
// All values >= 0 so bf16 bit ordering == value ordering; integer max/min is exact.
template<bool F32OUT>
__global__ void hop_kernel(const unsigned short* __restrict__ prev,
                           const int* __restrict__ starts, const int* __restrict__ ends,
                           const unsigned short* __restrict__ stails,
                           void* __restrict__ outp, int nNodes) {
    int wid  = blockIdx.x * (blockDim.x >> 6) + (threadIdx.x >> 6);
    int lane = threadIdx.x & 63;
    if (wid >= nNodes) return;
    int start = starts[wid], end = ends[wid];
    bool isMin = (!F32OUT) && (wid >= NV + NC);
    unsigned acc = isMin ? 0x7F80u : 0u;   // +inf / 0
    for (int k = start; k < end; k += 64) {
        int m = end - k; if (m > 64) m = 64;
        int tv = (lane < m) ? (int)stails[k + lane] : 0;
        int j = 0;
        for (; j + 4 <= m; j += 4) {
            int t0 = __shfl(tv, j), t1 = __shfl(tv, j + 1);
            int t2 = __shfl(tv, j + 2), t3 = __shfl(tv, j + 3);
            unsigned v0 = prev[t0 * D + lane];
            unsigned v1 = prev[t1 * D + lane];
            unsigned v2 = prev[t2 * D + lane];
            unsigned v3 = prev[t3 * D + lane];
            if (isMin) acc = min(min(acc, v0), min(v1, min(v2, v3)));
            else       acc = max(max(acc, v0), max(v1, max(v2, v3)));
        }
        for (; j < m; ++j) {
            unsigned v = prev[__shfl(tv, j) * D + lane];
            acc = isMin ? min(acc, v) : max(acc, v);
        }
    }
    if (isMin && start >= end) acc = 0;    // empty segment -> 0
    if (F32OUT) ((float*)outp)[(size_t)wid * D + lane] = __uint_as_float(acc << 16);
    else ((unsigned short*)outp)[(size_t)wid * D + lane] = (unsigned short)acc;
}

extern "C" void kernel_launch(void* const* d_in, const int* in_sizes, int n_in,
                              void* d_out, int out_size, void* d_ws, size_t ws_size,
                              hipStream_t stream) {
    const float* visit_offset = (const float*)d_in[1];
    const float* ccs_offset   = (const float*)d_in[3];
    const float* icd_offset   = (const float*)d_in[5];
    const int*   head         = (const int*)d_in[6];
    const int*   tail         = (const int*)d_in[7];
    float*       out          = (float*)d_out;

    char* ws = (char*)d_ws;
    unsigned short* off0   = (unsigned short*)(ws);                        // 3.88 MB
    unsigned short* off1   = (unsigned short*)(ws + (4u << 20));           // 3.88 MB
    unsigned*       pairs  = (unsigned*)      (ws + (8u << 20));           // 6 MB
    unsigned short* stails = (unsigned short*)(ws + (14u << 20));          // 3 MB
    int*            starts = (int*)           (ws + (17u << 20));          // 121 KB
    int*            ends   = (int*)           (ws + (17u << 20) + (256u << 10));
    int*            gcur   = (int*)           (ws + (17u << 20) + (512u << 10));

    hipMemsetAsync(gcur, 0, NB * sizeof(int), stream);

    zero_kernel<<<(NV * 16 + 255) / 256, 256, 0, stream>>>((float4*)out, NV * 16);
    init_off_kernel<<<(NN * 16 + 255) / 256, 256, 0, stream>>>(
        (const float4*)visit_offset, (const float4*)ccs_offset, (const float4*)icd_offset, off0);
    bin_kernel<<<NBLK_BIN, 256, 0, stream>>>(head, tail, gcur, pairs);
    bucket_sort_kernel<<<NB, 256, 0, stream>>>(pairs, gcur, stails, starts, ends);

    // hop 1: all NN nodes, off0 -> off1 (bf16 bits)
    hop_kernel<false><<<(NN + 3) / 4, 256, 0, stream>>>(off0, starts, ends, stails, off1, NN);
    // hop 2: only visit nodes; write f32 directly into d_out second half
    hop_kernel<true><<<(NV + 3) / 4, 256, 0, stream>>>(off1, starts, ends, stails,
                                                       out + (size_t)NV * D, NV);
}

// Round 8
// 163.570 us; speedup vs baseline: 1.9571x; 1.0770x over previous
//
#include <hip/hip_runtime.h>

#define NV 20000
#define NC 300
#define NI 10000
#define NN 30300   // NV + NC + NI
#define NE 1000000
#define D  64

#define NB     128          // buckets for CSR build
#define BNODES 237          // ceil(NN / NB); 128*237 = 30336 >= 30300
#define CAP    12288        // per-bucket edge capacity (mean 7822, +51 sigma)
#define BIN_CHUNK 2048
#define NBLK_BIN ((NE + BIN_CHUNK - 1) / BIN_CHUNK)   // 489

__device__ __forceinline__ unsigned short f2bf(float x) {
    // round-to-nearest-even f32 -> bf16; x is finite and >= 0 here
    unsigned u = __float_as_uint(x);
    u += 0x7FFFu + ((u >> 16) & 1u);
    return (unsigned short)(u >> 16);
}

// ------ fused: all_off = relu(concat(offsets)) as bf16 bits; zero out[:NV*D] -----
__global__ void init_off_kernel(const float4* __restrict__ vo, const float4* __restrict__ co,
                                const float4* __restrict__ io, unsigned short* __restrict__ buf,
                                float4* __restrict__ outz) {
    int i = blockIdx.x * blockDim.x + threadIdx.x;   // over NN*16 float4s
    if (i >= NN * 16) return;
    if (i < NV * 16) outz[i] = make_float4(0.f, 0.f, 0.f, 0.f);
    int n = i >> 4;
    float4 v;
    if (n < NV)            v = vo[i];
    else if (n < NV + NC)  v = co[i - NV * 16];
    else                   v = io[i - (NV + NC) * 16];
    ushort4 o;
    o.x = f2bf(fmaxf(v.x, 0.f));
    o.y = f2bf(fmaxf(v.y, 0.f));
    o.z = f2bf(fmaxf(v.z, 0.f));
    o.w = f2bf(fmaxf(v.w, 0.f));
    *reinterpret_cast<ushort4*>(buf + (size_t)i * 4) = o;
}

// ---------------- pass B: bin edges into 128 bucket regions (packed head|tail) ---
__global__ void bin_kernel(const int* __restrict__ head, const int* __restrict__ tail,
                           int* __restrict__ gcur, unsigned* __restrict__ pairs) {
    __shared__ int hist[NB];
    __shared__ int base[NB];
    int t = threadIdx.x;
    int e0 = blockIdx.x * BIN_CHUNK;
    if (t < NB) hist[t] = 0;
    __syncthreads();
    int hs[8], ts[8];
    if (e0 + BIN_CHUNK <= NE) {
        const int4* h4 = reinterpret_cast<const int4*>(head + e0);
        const int4* t4 = reinterpret_cast<const int4*>(tail + e0);
        int4 ha = h4[t], hb = h4[256 + t];
        int4 ta = t4[t], tb = t4[256 + t];
        hs[0] = ha.x; hs[1] = ha.y; hs[2] = ha.z; hs[3] = ha.w;
        hs[4] = hb.x; hs[5] = hb.y; hs[6] = hb.z; hs[7] = hb.w;
        ts[0] = ta.x; ts[1] = ta.y; ts[2] = ta.z; ts[3] = ta.w;
        ts[4] = tb.x; ts[5] = tb.y; ts[6] = tb.z; ts[7] = tb.w;
#pragma unroll
        for (int i = 0; i < 8; i++) atomicAdd(&hist[hs[i] / BNODES], 1);
    } else {
#pragma unroll
        for (int i = 0; i < 8; i++) {
            int e = e0 + i * 256 + t;
            if (e < NE) {
                hs[i] = head[e]; ts[i] = tail[e];
                atomicAdd(&hist[hs[i] / BNODES], 1);
            } else hs[i] = -1;
        }
    }
    __syncthreads();
    if (t < NB) {
        int c = hist[t];
        base[t] = c ? atomicAdd(&gcur[t], c) : 0;
        hist[t] = 0;   // reuse as local cursor
    }
    __syncthreads();
#pragma unroll
    for (int i = 0; i < 8; i++) {
        if (hs[i] >= 0) {
            int b = hs[i] / BNODES;
            int pos = base[b] + atomicAdd(&hist[b], 1);
            if (pos < CAP)
                pairs[(size_t)b * CAP + pos] = ((unsigned)hs[i] << 15) | (unsigned)ts[i];
        }
    }
}

// ---------------- pass C: per-bucket node sort in LDS -> CSR (no amplification) --
__global__ void bucket_sort_kernel(const unsigned* __restrict__ pairs, const int* __restrict__ gcur,
                                   unsigned short* __restrict__ stails,
                                   int* __restrict__ starts, int* __restrict__ ends) {
    __shared__ unsigned short staging[CAP];   // 24 KB
    __shared__ int cnt_l[256];
    __shared__ int scan_s[256];
    __shared__ int cur[256];
    int b = blockIdx.x, t = threadIdx.x;
    int node0 = b * BNODES;
    int nn = min(BNODES, NN - node0);
    int cnt = min(gcur[b], CAP);
    cnt_l[t] = 0;
    __syncthreads();
    const unsigned* P = pairs + (size_t)b * CAP;
    for (int i = t; i < cnt; i += 256) {
        int local = (int)(P[i] >> 15) - node0;
        atomicAdd(&cnt_l[local], 1);
    }
    __syncthreads();
    int v = cnt_l[t];
    scan_s[t] = v;
    __syncthreads();
    for (int off = 1; off < 256; off <<= 1) {
        int tv = (t >= off) ? scan_s[t - off] : 0;
        __syncthreads();
        scan_s[t] += tv;
        __syncthreads();
    }
    int excl = scan_s[t] - v;
    cur[t] = excl;
    if (t < nn) {
        starts[node0 + t] = b * CAP + excl;
        ends[node0 + t]   = b * CAP + excl + v;
    }
    __syncthreads();
    for (int i = t; i < cnt; i += 256) {
        unsigned p = P[i];
        int local = (int)(p >> 15) - node0;
        int pos = atomicAdd(&cur[local], 1);
        staging[pos] = (unsigned short)(p & 0x7FFFu);
    }
    __syncthreads();
    for (int i = t; i < cnt; i += 256)
        stails[(size_t)b * CAP + i] = staging[i];
}

// ---------------- one hop: segmented max/min on bf16 bits, 4 edges/round ---------
// Lane layout: grp = lane>>4 (edge slot), sub = lane&15 (8B = 4 dims of the row).
// Min is done as max over complemented u16 (values >= 0 so bit order == value order).
template<bool F32OUT>
__global__ __launch_bounds__(256) void hop_kernel(
        const unsigned short* __restrict__ prev,
        const int* __restrict__ starts, const int* __restrict__ ends,
        const unsigned short* __restrict__ stails,
        void* __restrict__ outp, int nNodes) {
    int wid  = blockIdx.x * 4 + (threadIdx.x >> 6);
    int lane = threadIdx.x & 63;
    if (wid >= nNodes) return;
    int start = starts[wid], end = ends[wid];
    bool isMin = (!F32OUT) && (wid >= NV + NC);
    unsigned mm = isMin ? 0xFFFFFFFFu : 0u;
    int grp = lane >> 4, sub = lane & 15;
    const unsigned short* rowb = prev + sub * 4;
    unsigned a0 = 0, a1 = 0, a2 = 0, a3 = 0;   // complement-space accumulators
    int k = start;
    for (; k + 16 <= end; k += 16) {           // 16 edges per iteration
#pragma unroll
        for (int r = 0; r < 4; ++r) {
            int tix = (int)stails[k + r * 4 + grp];
            uint2 v = *reinterpret_cast<const uint2*>(rowb + tix * D);
            v.x ^= mm; v.y ^= mm;
            a0 = max(a0, v.x & 0xFFFFu); a1 = max(a1, v.x >> 16);
            a2 = max(a2, v.y & 0xFFFFu); a3 = max(a3, v.y >> 16);
        }
    }
    for (; k < end; k += 4) {                  // tail: 4 edges per round
        int e = k + grp;
        int tix = (int)stails[(e < end) ? e : (end - 1)];
        uint2 v = *reinterpret_cast<const uint2*>(rowb + tix * D);
        if (e >= end) { v.x = mm; v.y = mm; }  // identity after xor
        v.x ^= mm; v.y ^= mm;
        a0 = max(a0, v.x & 0xFFFFu); a1 = max(a1, v.x >> 16);
        a2 = max(a2, v.y & 0xFFFFu); a3 = max(a3, v.y >> 16);
    }
    // reduce across the 4 edge-slots (lanes differing in bits 4,5)
    a0 = max(a0, (unsigned)__shfl_xor((int)a0, 16)); a0 = max(a0, (unsigned)__shfl_xor((int)a0, 32));
    a1 = max(a1, (unsigned)__shfl_xor((int)a1, 16)); a1 = max(a1, (unsigned)__shfl_xor((int)a1, 32));
    a2 = max(a2, (unsigned)__shfl_xor((int)a2, 16)); a2 = max(a2, (unsigned)__shfl_xor((int)a2, 32));
    a3 = max(a3, (unsigned)__shfl_xor((int)a3, 16)); a3 = max(a3, (unsigned)__shfl_xor((int)a3, 32));
    unsigned m16 = mm & 0xFFFFu;
    unsigned r0 = a0 ^ m16, r1 = a1 ^ m16, r2 = a2 ^ m16, r3 = a3 ^ m16;
    if (start >= end) { r0 = r1 = r2 = r3 = 0; }   // empty segment -> 0
    if (grp == 0) {
        if (F32OUT) {
            float4 o = make_float4(__uint_as_float(r0 << 16), __uint_as_float(r1 << 16),
                                   __uint_as_float(r2 << 16), __uint_as_float(r3 << 16));
            reinterpret_cast<float4*>(outp)[(size_t)wid * 16 + sub] = o;
        } else {
            ushort4 o;
            o.x = (unsigned short)r0; o.y = (unsigned short)r1;
            o.z = (unsigned short)r2; o.w = (unsigned short)r3;
            reinterpret_cast<ushort4*>(outp)[(size_t)wid * 16 + sub] = o;
        }
    }
}

extern "C" void kernel_launch(void* const* d_in, const int* in_sizes, int n_in,
                              void* d_out, int out_size, void* d_ws, size_t ws_size,
                              hipStream_t stream) {
    const float* visit_offset = (const float*)d_in[1];
    const float* ccs_offset   = (const float*)d_in[3];
    const float* icd_offset   = (const float*)d_in[5];
    const int*   head         = (const int*)d_in[6];
    const int*   tail         = (const int*)d_in[7];
    float*       out          = (float*)d_out;

    char* ws = (char*)d_ws;
    unsigned short* off0   = (unsigned short*)(ws);                        // 3.88 MB
    unsigned short* off1   = (unsigned short*)(ws + (4u << 20));           // 3.88 MB
    unsigned*       pairs  = (unsigned*)      (ws + (8u << 20));           // 6 MB
    unsigned short* stails = (unsigned short*)(ws + (14u << 20));          // 3 MB
    int*            starts = (int*)           (ws + (17u << 20));          // 121 KB
    int*            ends   = (int*)           (ws + (17u << 20) + (256u << 10));
    int*            gcur   = (int*)           (ws + (17u << 20) + (512u << 10));

    hipMemsetAsync(gcur, 0, NB * sizeof(int), stream);

    init_off_kernel<<<(NN * 16 + 255) / 256, 256, 0, stream>>>(
        (const float4*)visit_offset, (const float4*)ccs_offset, (const float4*)icd_offset,
        off0, (float4*)out);
    bin_kernel<<<NBLK_BIN, 256, 0, stream>>>(head, tail, gcur, pairs);
    bucket_sort_kernel<<<NB, 256, 0, stream>>>(pairs, gcur, stails, starts, ends);

    // hop 1: all NN nodes, off0 -> off1 (bf16 bits)
    hop_kernel<false><<<(NN + 3) / 4, 256, 0, stream>>>(off0, starts, ends, stails, off1, NN);
    // hop 2: only visit nodes; write f32 directly into d_out second half
    hop_kernel<true><<<(NV + 3) / 4, 256, 0, stream>>>(off1, starts, ends, stails,
                                                       out + (size_t)NV * D, NV);
}

// Round 9
// 153.300 us; speedup vs baseline: 2.0883x; 1.0670x over previous
//
#include <hip/hip_runtime.h>

#define NV 20000
#define NC 300
#define NI 10000
#define NN 30300   // NV + NC + NI
#define NE 1000000
#define D  64

#define NB     512          // buckets for CSR build (one block each, 2/CU)
#define BNODES 60           // ceil(NN / NB); 512*60 = 30720 >= 30300
#define CAP    2560         // per-bucket edge capacity (mean 1980, +13 sigma)
#define BIN_CHUNK 2048
#define NBLK_BIN ((NE + BIN_CHUNK - 1) / BIN_CHUNK)   // 489

__device__ __forceinline__ unsigned short f2bf(float x) {
    // round-to-nearest-even f32 -> bf16; x is finite and >= 0 here
    unsigned u = __float_as_uint(x);
    u += 0x7FFFu + ((u >> 16) & 1u);
    return (unsigned short)(u >> 16);
}

// -- fused: all_off = relu(concat(offsets)) as bf16 bits; zero out[:NV*D]; gcur=0 --
__global__ void init_off_kernel(const float4* __restrict__ vo, const float4* __restrict__ co,
                                const float4* __restrict__ io, unsigned short* __restrict__ buf,
                                float4* __restrict__ outz, int* __restrict__ gcur) {
    int i = blockIdx.x * blockDim.x + threadIdx.x;   // over NN*16 float4s
    if (blockIdx.x == 0) {                           // NB=512 counters
        gcur[threadIdx.x] = 0;
        gcur[threadIdx.x + 256] = 0;
    }
    if (i >= NN * 16) return;
    if (i < NV * 16) outz[i] = make_float4(0.f, 0.f, 0.f, 0.f);
    int n = i >> 4;
    float4 v;
    if (n < NV)            v = vo[i];
    else if (n < NV + NC)  v = co[i - NV * 16];
    else                   v = io[i - (NV + NC) * 16];
    ushort4 o;
    o.x = f2bf(fmaxf(v.x, 0.f));
    o.y = f2bf(fmaxf(v.y, 0.f));
    o.z = f2bf(fmaxf(v.z, 0.f));
    o.w = f2bf(fmaxf(v.w, 0.f));
    *reinterpret_cast<ushort4*>(buf + (size_t)i * 4) = o;
}

// ---------------- pass B: bin edges into 512 bucket regions (packed head|tail) ---
__global__ void bin_kernel(const int* __restrict__ head, const int* __restrict__ tail,
                           int* __restrict__ gcur, unsigned* __restrict__ pairs) {
    __shared__ int hist[NB];
    __shared__ int base[NB];
    int t = threadIdx.x;
    int e0 = blockIdx.x * BIN_CHUNK;
    for (int j = t; j < NB; j += 256) hist[j] = 0;
    __syncthreads();
    int hs[8], ts[8];
    if (e0 + BIN_CHUNK <= NE) {
        const int4* h4 = reinterpret_cast<const int4*>(head + e0);
        const int4* t4 = reinterpret_cast<const int4*>(tail + e0);
        int4 ha = h4[t], hb = h4[256 + t];
        int4 ta = t4[t], tb = t4[256 + t];
        hs[0] = ha.x; hs[1] = ha.y; hs[2] = ha.z; hs[3] = ha.w;
        hs[4] = hb.x; hs[5] = hb.y; hs[6] = hb.z; hs[7] = hb.w;
        ts[0] = ta.x; ts[1] = ta.y; ts[2] = ta.z; ts[3] = ta.w;
        ts[4] = tb.x; ts[5] = tb.y; ts[6] = tb.z; ts[7] = tb.w;
#pragma unroll
        for (int i = 0; i < 8; i++) atomicAdd(&hist[hs[i] / BNODES], 1);
    } else {
#pragma unroll
        for (int i = 0; i < 8; i++) {
            int e = e0 + i * 256 + t;
            if (e < NE) {
                hs[i] = head[e]; ts[i] = tail[e];
                atomicAdd(&hist[hs[i] / BNODES], 1);
            } else hs[i] = -1;
        }
    }
    __syncthreads();
    for (int j = t; j < NB; j += 256) {
        int c = hist[j];
        base[j] = c ? atomicAdd(&gcur[j], c) : 0;
        hist[j] = 0;   // reuse as local cursor
    }
    __syncthreads();
#pragma unroll
    for (int i = 0; i < 8; i++) {
        if (hs[i] >= 0) {
            int b = hs[i] / BNODES;
            int pos = base[b] + atomicAdd(&hist[b], 1);
            if (pos < CAP)
                pairs[(size_t)b * CAP + pos] = ((unsigned)hs[i] << 15) | (unsigned)ts[i];
        }
    }
}

// ---------------- pass C: per-bucket node sort in LDS -> CSR (no amplification) --
__global__ void bucket_sort_kernel(const unsigned* __restrict__ pairs, const int* __restrict__ gcur,
                                   unsigned short* __restrict__ stails,
                                   int* __restrict__ starts, int* __restrict__ ends) {
    __shared__ unsigned short staging[CAP];   // 5 KB
    __shared__ int cnt_l[256];
    __shared__ int scan_s[256];
    __shared__ int cur[256];
    int b = blockIdx.x, t = threadIdx.x;
    int node0 = b * BNODES;
    int nn = min(BNODES, NN - node0);          // may be <=0 for trailing buckets
    int cnt = min(gcur[b], CAP);
    cnt_l[t] = 0;
    __syncthreads();
    const unsigned* P = pairs + (size_t)b * CAP;
    for (int i = t; i < cnt; i += 256) {
        int local = (int)(P[i] >> 15) - node0;
        atomicAdd(&cnt_l[local], 1);
    }
    __syncthreads();
    int v = cnt_l[t];
    scan_s[t] = v;
    __syncthreads();
    for (int off = 1; off < 256; off <<= 1) {
        int tv = (t >= off) ? scan_s[t - off] : 0;
        __syncthreads();
        scan_s[t] += tv;
        __syncthreads();
    }
    int excl = scan_s[t] - v;
    cur[t] = excl;
    if (t < nn) {
        starts[node0 + t] = b * CAP + excl;
        ends[node0 + t]   = b * CAP + excl + v;
    }
    __syncthreads();
    for (int i = t; i < cnt; i += 256) {
        unsigned p = P[i];
        int local = (int)(p >> 15) - node0;
        int pos = atomicAdd(&cur[local], 1);
        staging[pos] = (unsigned short)(p & 0x7FFFu);
    }
    __syncthreads();
    for (int i = t; i < cnt; i += 256)
        stails[(size_t)b * CAP + i] = staging[i];
}

// -------- one hop: segmented max/min on bf16 bits, 16B/lane, 8 edges/round -------
// Lane layout: grp = lane>>3 (edge slot), sub = lane&7 (16B = 8 dims of the row).
// Tail indices preloaded coalesced per 64-edge chunk, broadcast via shfl.
// Min via complemented u16 max (values >= 0 so bit order == value order).
template<bool F32OUT>
__global__ __launch_bounds__(256) void hop_kernel(
        const unsigned short* __restrict__ prev,
        const int* __restrict__ starts, const int* __restrict__ ends,
        const unsigned short* __restrict__ stails,
        void* __restrict__ outp, int nNodes) {
    int wid  = blockIdx.x * 4 + (threadIdx.x >> 6);
    int lane = threadIdx.x & 63;
    if (wid >= nNodes) return;
    int start = starts[wid], end = ends[wid];
    bool isMin = (!F32OUT) && (wid >= NV + NC);
    unsigned mm = isMin ? 0xFFFFFFFFu : 0u;
    int grp = lane >> 3, sub = lane & 7;
    const unsigned short* rowb = prev + sub * 8;      // this lane's 16B of each row
    unsigned a0 = 0, a1 = 0, a2 = 0, a3 = 0,          // complement-space accumulators
             a4 = 0, a5 = 0, a6 = 0, a7 = 0;
    for (int base = start; base < end; base += 64) {
        int cdeg = end - base; if (cdeg > 64) cdeg = 64;
        int tv = (lane < cdeg) ? (int)stails[base + lane] : 0;   // coalesced preload
        for (int r0 = 0; r0 < cdeg; r0 += 32) {       // 32 edges per super-iteration
#pragma unroll
            for (int r = 0; r < 4; ++r) {
                int e  = r0 + r * 8 + grp;
                int ec = (e < cdeg) ? e : (cdeg - 1);
                int tix = __shfl(tv, ec);
                uint4 v = *reinterpret_cast<const uint4*>(rowb + tix * D);
                unsigned live = (e < cdeg) ? 0xFFFFFFFFu : 0u;   // pad -> 0 in cmpl space
                v.x = (v.x ^ mm) & live; v.y = (v.y ^ mm) & live;
                v.z = (v.z ^ mm) & live; v.w = (v.w ^ mm) & live;
                a0 = max(a0, v.x & 0xFFFFu); a1 = max(a1, v.x >> 16);
                a2 = max(a2, v.y & 0xFFFFu); a3 = max(a3, v.y >> 16);
                a4 = max(a4, v.z & 0xFFFFu); a5 = max(a5, v.z >> 16);
                a6 = max(a6, v.w & 0xFFFFu); a7 = max(a7, v.w >> 16);
            }
        }
    }
    // reduce across the 8 edge-slots (lanes differing in bits 3,4,5)
#pragma unroll
    for (int d = 8; d < 64; d <<= 1) {
        a0 = max(a0, (unsigned)__shfl_xor((int)a0, d));
        a1 = max(a1, (unsigned)__shfl_xor((int)a1, d));
        a2 = max(a2, (unsigned)__shfl_xor((int)a2, d));
        a3 = max(a3, (unsigned)__shfl_xor((int)a3, d));
        a4 = max(a4, (unsigned)__shfl_xor((int)a4, d));
        a5 = max(a5, (unsigned)__shfl_xor((int)a5, d));
        a6 = max(a6, (unsigned)__shfl_xor((int)a6, d));
        a7 = max(a7, (unsigned)__shfl_xor((int)a7, d));
    }
    unsigned m16 = mm & 0xFFFFu;
    unsigned r0v = a0 ^ m16, r1v = a1 ^ m16, r2v = a2 ^ m16, r3v = a3 ^ m16;
    unsigned r4v = a4 ^ m16, r5v = a5 ^ m16, r6v = a6 ^ m16, r7v = a7 ^ m16;
    if (start >= end) { r0v=r1v=r2v=r3v=r4v=r5v=r6v=r7v=0; }   // empty segment -> 0
    if (grp == 0) {
        if (F32OUT) {
            float4 oa = make_float4(__uint_as_float(r0v << 16), __uint_as_float(r1v << 16),
                                    __uint_as_float(r2v << 16), __uint_as_float(r3v << 16));
            float4 ob = make_float4(__uint_as_float(r4v << 16), __uint_as_float(r5v << 16),
                                    __uint_as_float(r6v << 16), __uint_as_float(r7v << 16));
            float4* op = reinterpret_cast<float4*>(outp) + (size_t)wid * 16 + sub * 2;
            op[0] = oa; op[1] = ob;
        } else {
            uint4 o;
            o.x = r0v | (r1v << 16); o.y = r2v | (r3v << 16);
            o.z = r4v | (r5v << 16); o.w = r6v | (r7v << 16);
            reinterpret_cast<uint4*>(outp)[(size_t)wid * 8 + sub] = o;
        }
    }
}

extern "C" void kernel_launch(void* const* d_in, const int* in_sizes, int n_in,
                              void* d_out, int out_size, void* d_ws, size_t ws_size,
                              hipStream_t stream) {
    const float* visit_offset = (const float*)d_in[1];
    const float* ccs_offset   = (const float*)d_in[3];
    const float* icd_offset   = (const float*)d_in[5];
    const int*   head         = (const int*)d_in[6];
    const int*   tail         = (const int*)d_in[7];
    float*       out          = (float*)d_out;

    char* ws = (char*)d_ws;
    unsigned short* off0   = (unsigned short*)(ws);                        // 3.88 MB
    unsigned short* off1   = (unsigned short*)(ws + (4u << 20));           // 3.88 MB
    unsigned*       pairs  = (unsigned*)      (ws + (8u << 20));           // 5.24 MB
    unsigned short* stails = (unsigned short*)(ws + (14u << 20));          // 2.62 MB
    int*            starts = (int*)           (ws + (17u << 20));          // 121 KB
    int*            ends   = (int*)           (ws + (17u << 20) + (256u << 10));
    int*            gcur   = (int*)           (ws + (17u << 20) + (512u << 10));

    init_off_kernel<<<(NN * 16 + 255) / 256, 256, 0, stream>>>(
        (const float4*)visit_offset, (const float4*)ccs_offset, (const float4*)icd_offset,
        off0, (float4*)out, gcur);
    bin_kernel<<<NBLK_BIN, 256, 0, stream>>>(head, tail, gcur, pairs);
    bucket_sort_kernel<<<NB, 256, 0, stream>>>(pairs, gcur, stails, starts, ends);

    // hop 1: all NN nodes, off0 -> off1 (bf16 bits)
    hop_kernel<false><<<(NN + 3) / 4, 256, 0, stream>>>(off0, starts, ends, stails, off1, NN);
    // hop 2: only visit nodes; write f32 directly into d_out second half
    hop_kernel<true><<<(NV + 3) / 4, 256, 0, stream>>>(off1, starts, ends, stails,
                                                       out + (size_t)NV * D, NV);
}